// Round 14
// baseline (191.208 us; speedup 1.0000x reference)
//
#include <hip/hip_runtime.h>
#include <hip/hip_bf16.h>

// GraphConv x3 + ReLU + log_softmax on MI355X — bf16/MFMA pipeline.
// LEDGER (keep):
// R11/R16/R12: place fusion/spreading dead ends — place ~10us, structure
//      off-limits (3 fails).
// R13/R14: quartered-T L2 pinning impossible; NT 2B SCALAR stores bypass
//      write-combining (regression). NT on 16B grouped stores is OK.
// R15 (WIN): swizzled-LDS transpose epilogue -> 16B coalesced stores.
// R17/R18/R22 (currency, refined): after wave coalescing each edge's row
//      is ONE line transaction; fp8 row=128B=1 line is the line floor.
// R19: TLP beyond per-CU MSHR cap adds nothing.
// R20/R21 (WINs): agg fused as next mm's prologue; 32-row tiles, 1.63
//      rounds; x staged fp32-direct; prep+place merged LDS-free.
// R23: (a) NT-hint ALL streaming accesses (esrc/Sprev/x loads, T/S
//      epilogue 16B stores) so each XCD's 4MB L2 is reserved for the
//      gathered T window. (b) esrc uint16. NOTE: NT builtins need
//      ext_vector types (ux4/ux2/fx4), NOT HIP uint4/float4 classes.
//      Pre-commit: null => gather at MSHR*L3-latency floor.

#define N_NODES 40000
#define N_EDGES 640000
#define PAD_NODES 40064        // 1252 * 32
#define DEG_CAP   40960
#define ROW_CAP   64           // esrc slots per node

typedef float v4f __attribute__((ext_vector_type(4)));
typedef float v2f __attribute__((ext_vector_type(2)));
typedef short short8 __attribute__((ext_vector_type(8)));
typedef unsigned ux4 __attribute__((ext_vector_type(4)));
typedef unsigned ux2 __attribute__((ext_vector_type(2)));
typedef float fx4 __attribute__((ext_vector_type(4)));

#define NTL(p)    __builtin_nontemporal_load(p)
#define NTS(v, p) __builtin_nontemporal_store(v, p)

__device__ inline unsigned short f2b(float f) {  // RNE fp32->bf16
    unsigned u = __float_as_uint(f);
    return (unsigned short)((u + 0x7fffu + ((u >> 16) & 1u)) >> 16);
}

// bf16 -> fp8 e4m3 (OCP), RNE, FTZ below 2^-6, clamp 448 (fallback path).
__device__ inline unsigned b2f8(unsigned short us) {
    unsigned s  = ((unsigned)us >> 8) & 0x80u;
    unsigned mag = us & 0x7fffu;
    unsigned e8 = mag >> 7, m7 = mag & 0x7fu;
    unsigned out;
    if (e8 < 121u) out = 0u;
    else if (e8 > 135u) out = 0x7eu;
    else {
        unsigned e4 = e8 - 120u;
        unsigned r  = (m7 + 7u + ((m7 >> 4) & 1u)) >> 4;
        if (r == 8u) { r = 0u; e4++; }
        out = (e4 > 15u || (e4 == 15u && r > 6u)) ? 0x7eu : ((e4 << 3) | r);
    }
    return s | out;
}

__device__ inline unsigned pack4_fp8(float f0, float f1, float f2, float f3) {
#if __has_builtin(__builtin_amdgcn_cvt_pk_fp8_f32)
    int w = __builtin_amdgcn_cvt_pk_fp8_f32(f0, f1, 0, false);
    w = __builtin_amdgcn_cvt_pk_fp8_f32(f2, f3, w, true);
    return (unsigned)w;
#else
    return b2f8(f2b(f0)) | (b2f8(f2b(f1)) << 8) |
           (b2f8(f2b(f2)) << 16) | (b2f8(f2b(f3)) << 24);
#endif
}

#if __has_builtin(__builtin_amdgcn_cvt_f32_fp8)
#define F8TOF(w, sel) __builtin_amdgcn_cvt_f32_fp8((int)(w), (sel))
#else
__device__ inline float f8tof_(unsigned b) {
    unsigned e = (b >> 3) & 15u;
    unsigned bits = ((b & 0x80u) << 24) |
                    (e ? (((e + 120u) << 23) | ((b & 7u) << 20)) : 0u);
    return __uint_as_float(bits);
}
#define F8TOF(w, sel) f8tof_(((unsigned)(w) >> ((sel) * 8)) & 0xffu)
#endif

__device__ inline void addp(v2f* a, ux4 q) {         // 8 bf16
    v2f t0 = { __uint_as_float(q.x << 16), __uint_as_float(q.x & 0xffff0000u) };
    v2f t1 = { __uint_as_float(q.y << 16), __uint_as_float(q.y & 0xffff0000u) };
    v2f t2 = { __uint_as_float(q.z << 16), __uint_as_float(q.z & 0xffff0000u) };
    v2f t3 = { __uint_as_float(q.w << 16), __uint_as_float(q.w & 0xffff0000u) };
    a[0] += t0; a[1] += t1; a[2] += t2; a[3] += t3;
}
// 4 fp8 -> 2 v2f; packed-cvt path does 2 fp8 per instruction.
__device__ inline void addp8w(v2f* a, unsigned w) {
#if __has_builtin(__builtin_amdgcn_cvt_pk_f32_fp8)
    v2f lo = __builtin_amdgcn_cvt_pk_f32_fp8((int)w, false);
    v2f hi = __builtin_amdgcn_cvt_pk_f32_fp8((int)w, true);
    a[0] += lo; a[1] += hi;
#else
    v2f t0 = { F8TOF(w, 0), F8TOF(w, 1) };
    v2f t1 = { F8TOF(w, 2), F8TOF(w, 3) };
    a[0] += t0; a[1] += t1;
#endif
}
__device__ inline void addp16(v2f* a, ux4 q) {       // 16 fp8 -> a[0..7]
    addp8w(a + 0, q.x); addp8w(a + 2, q.y);
    addp8w(a + 4, q.z); addp8w(a + 6, q.w);
}

// ---------------------------------------------------------------- prep+place
// LDS-free fused kernel: blocks [0,2500) place edges (full occupancy);
// blocks [2500,2820) do W casts. deg zeroed by hipMemsetAsync.
// esrc is uint16; scatter store stays REGULAR (2B NT = R14 trap).
__global__ __launch_bounds__(256) void prep_place_kernel(const int* __restrict__ src,
                                                         const int* __restrict__ dst,
                                                         int* __restrict__ deg,
                                                         unsigned short* __restrict__ esrc,
                                                         const float* __restrict__ Wr0, const float* __restrict__ Ws0,
                                                         const float* __restrict__ Wr1, const float* __restrict__ Ws1,
                                                         const float* __restrict__ Wr2, const float* __restrict__ Ws2,
                                                         unsigned short* __restrict__ Wt0,
                                                         unsigned short* __restrict__ Wt1,
                                                         unsigned short* __restrict__ Wt2) {
    const int bid = blockIdx.x;
    if (bid < 2500) {
        int e = bid * 256 + threadIdx.x;
        if (e < N_EDGES) {
            int d = NTL(dst + e);
            int s = NTL(src + e);
            int r = atomicAdd(&deg[d], 1);
            if (r < ROW_CAP) esrc[(size_t)d * ROW_CAP + r] = (unsigned short)s;
        }
    } else {
        int t = (bid - 2500) * 256 + threadIdx.x;   // 0..81919
        if (t < 32768) {
            int n = t >> 7, k = t & 127;
            const float* W = (n < 128) ? Wr0 : Ws0;
            Wt0[t] = f2b(W[k * 128 + (n & 127)]);
        } else if (t < 65536) {
            int u = t - 32768;
            int n = u >> 7, k = u & 127;
            const float* W = (n < 128) ? Wr1 : Ws1;
            Wt1[u] = f2b(W[k * 128 + (n & 127)]);
        } else if (t < 81920) {
            int u = t - 65536;
            int n = u >> 7, k = u & 127;
            const float* W = (n < 64) ? Wr2 : Ws2;
            Wt2[u] = f2b(W[k * 64 + (n & 63)]);
        }
    }
}

// ---------------------------------------------------------------- fused mm
// Block owns 32 rows x full NB=2*DO cols; grid 1252; LDS = As 8KB +
// Bs 32/16KB; (256,3) -> 1.63 rounds. AGG: 8 lanes/node x 16 dims,
// 1 ux4/edge/lane fp8 gather (line floor). F32: stage fp32 x (NT).
// NT on esrc/Sprev/x loads + T/S epilogue stores — L2 reserved for the
// gathered T window. Gather loads stay CACHED (the point).
// node==N_NODES row forced zeros (dummy row for pad-slot gathers).
template <int DO, bool AGG, bool F32>
__global__ __launch_bounds__(256, 3) void mmf_kernel(const void* __restrict__ Ain,
                                                     const unsigned short* __restrict__ Sprev,
                                                     const float* __restrict__ brp,
                                                     const int* __restrict__ deg,
                                                     const unsigned short* __restrict__ esrc,
                                                     const unsigned short* __restrict__ Wt,
                                                     void* __restrict__ Tout,
                                                     unsigned short* __restrict__ Sout) {
    constexpr int NB  = 2 * DO;          // 256 or 128
    constexpr int NBW = NB / 4;          // cols per wave
    constexpr int CF  = NBW / 16;        // col frags per wave (4 or 2)

    __shared__ unsigned short AsMem[32 * 128];   // 8 KB
    __shared__ unsigned short BsMem[NB * 64];    // 32 KB (NB=256) / 16 KB
    ux4* As4 = (ux4*)AsMem;
    ux4* Bs4 = (ux4*)BsMem;

    const int tid  = threadIdx.x;
    const int m0   = blockIdx.x * 32;
    const int wave = tid >> 6;
    const int lane = tid & 63;
    const int qm   = lane & 15;
    const int hi   = lane >> 4;
    const int wcb  = wave * NBW;

    // ---- A: aggregate prologue / fp32 stage (gathers issued first)
    if (AGG) {
        const int noderow = tid >> 3;    // 0..31
        const int lane8   = tid & 7;     // dims lane8*16..+15
        const int n       = m0 + noderow;
        if (n < N_NODES) {
            int cnt = deg[n];
            if (cnt > ROW_CAP) cnt = ROW_CAP;
            const unsigned short* erow = esrc + (size_t)n * ROW_CAP;
            const ux4* T8 = (const ux4*)Ain;  // fp8 row = 8 ux4
            v2f acc[8];
#pragma unroll
            for (int i = 0; i < 8; i++) acc[i] = (v2f)(0.0f);
            for (int o = 0; o < cnt; o += 8) {
                ux4 iv = NTL((const ux4*)(const void*)(erow + o));  // 8 idx
                unsigned j0 = iv.x & 0xffffu, j1 = iv.x >> 16;
                unsigned j2 = iv.y & 0xffffu, j3 = iv.y >> 16;
                unsigned j4 = iv.z & 0xffffu, j5 = iv.z >> 16;
                unsigned j6 = iv.w & 0xffffu, j7 = iv.w >> 16;
                j0 = (o + 0 < cnt) ? j0 : N_NODES;
                j1 = (o + 1 < cnt) ? j1 : N_NODES;
                j2 = (o + 2 < cnt) ? j2 : N_NODES;
                j3 = (o + 3 < cnt) ? j3 : N_NODES;
                j4 = (o + 4 < cnt) ? j4 : N_NODES;
                j5 = (o + 5 < cnt) ? j5 : N_NODES;
                j6 = (o + 6 < cnt) ? j6 : N_NODES;
                j7 = (o + 7 < cnt) ? j7 : N_NODES;
                ux4 q0 = T8[(size_t)j0 * 8 + lane8];
                ux4 q1 = T8[(size_t)j1 * 8 + lane8];
                ux4 q2 = T8[(size_t)j2 * 8 + lane8];
                ux4 q3 = T8[(size_t)j3 * 8 + lane8];
                ux4 q4 = T8[(size_t)j4 * 8 + lane8];
                ux4 q5 = T8[(size_t)j5 * 8 + lane8];
                ux4 q6 = T8[(size_t)j6 * 8 + lane8];
                ux4 q7 = T8[(size_t)j7 * 8 + lane8];
                addp16(acc, q0); addp16(acc, q1); addp16(acc, q2); addp16(acc, q3);
                addp16(acc, q4); addp16(acc, q5); addp16(acc, q6); addp16(acc, q7);
            }
            // + S (bf16 exact, NT) + bias, relu, pack 16 dims -> 2 ux4
            ux4 sv0 = NTL((const ux4*)Sprev + (size_t)n * 16 + lane8 * 2);
            ux4 sv1 = NTL((const ux4*)Sprev + (size_t)n * 16 + lane8 * 2 + 1);
            addp(acc, sv0); addp(acc + 4, sv1);
            float vv[16];
#pragma unroll
            for (int j = 0; j < 16; j++) {
                float bj = brp[lane8 * 16 + j];
                vv[j] = fmaxf(((j & 1) ? acc[j >> 1].y : acc[j >> 1].x) + bj, 0.f);
            }
#pragma unroll
            for (int h = 0; h < 2; h++) {
                ux4 o;
                o.x = (unsigned)f2b(vv[h * 8 + 0]) | ((unsigned)f2b(vv[h * 8 + 1]) << 16);
                o.y = (unsigned)f2b(vv[h * 8 + 2]) | ((unsigned)f2b(vv[h * 8 + 3]) << 16);
                o.z = (unsigned)f2b(vv[h * 8 + 4]) | ((unsigned)f2b(vv[h * 8 + 5]) << 16);
                o.w = (unsigned)f2b(vv[h * 8 + 6]) | ((unsigned)f2b(vv[h * 8 + 7]) << 16);
                As4[noderow * 16 + ((lane8 * 2 + h) ^ (noderow & 7))] = o;
            }
        } else {
            ux4 z = (ux4)0u;
#pragma unroll
            for (int h = 0; h < 2; h++)
                As4[noderow * 16 + ((lane8 * 2 + h) ^ (noderow & 7))] = z;
        }
    } else if (F32) {
        const fx4* Xg = (const fx4*)Ain;             // row pitch 32 fx4
#pragma unroll
        for (int i = 0; i < 2; i++) {
            int idx = i * 256 + tid;                 // ux4 slot 0..511
            int row = idx >> 4, c = idx & 15;        // c = 8-dim chunk
            int gr = m0 + row;
            if (gr > N_NODES - 1) gr = N_NODES - 1;  // pad clamp
            fx4 a = NTL(Xg + (size_t)gr * 32 + c * 2);
            fx4 b = NTL(Xg + (size_t)gr * 32 + c * 2 + 1);
            ux4 o;
            o.x = (unsigned)f2b(a.x) | ((unsigned)f2b(a.y) << 16);
            o.y = (unsigned)f2b(a.z) | ((unsigned)f2b(a.w) << 16);
            o.z = (unsigned)f2b(b.x) | ((unsigned)f2b(b.y) << 16);
            o.w = (unsigned)f2b(b.z) | ((unsigned)f2b(b.w) << 16);
            As4[row * 16 + (c ^ (row & 7))] = o;
        }
    } else {
        const unsigned short* Ab = (const unsigned short*)Ain;
#pragma unroll
        for (int i = 0; i < 2; i++) {
            int idx = i * 256 + tid;
            int row = idx >> 4, c = idx & 15;
            int gr = m0 + row;
            if (gr > N_NODES - 1) gr = N_NODES - 1;
            As4[row * 16 + (c ^ (row & 7))] =
                NTL((const ux4*)(const void*)(Ab + (size_t)gr * 128 + c * 8));
        }
    }

    // ---- stage B half 0 (cached — reused by all blocks)
#pragma unroll
    for (int i = 0; i < NB * 8 / 256; i++) {
        int idx = i * 256 + tid;
        int row = idx >> 3, c8 = idx & 7;
        Bs4[row * 8 + (c8 ^ (row & 7))] =
            *(const ux4*)(Wt + (size_t)row * 128 + c8 * 8);
    }
    __syncthreads();

    // ---- MFMA: K=128 in 2 halves; Bs restaged between halves
    v4f acc[2][CF];
#pragma unroll
    for (int i = 0; i < 2; i++)
#pragma unroll
        for (int j = 0; j < CF; j++) acc[i][j] = (v4f)(0.0f);

#pragma unroll
    for (int half = 0; half < 2; half++) {
        if (half == 1) {
            __syncthreads();
#pragma unroll
            for (int i = 0; i < NB * 8 / 256; i++) {
                int idx = i * 256 + tid;
                int row = idx >> 3, c8 = idx & 7;
                Bs4[row * 8 + (c8 ^ (row & 7))] =
                    *(const ux4*)(Wt + (size_t)row * 128 + 64 + c8 * 8);
            }
            __syncthreads();
        }
#pragma unroll
        for (int ks = 0; ks < 2; ks++) {
            short8 af[2], bf[CF];
#pragma unroll
            for (int mi = 0; mi < 2; mi++) {
                const int r  = mi * 16 + qm;
                const int ca = half * 8 + ks * 4 + hi;
                af[mi] = *(const short8*)&As4[r * 16 + (ca ^ (r & 7))];
            }
#pragma unroll
            for (int ni = 0; ni < CF; ni++) {
                const int rb = wcb + ni * 16 + qm;
                const int cb = ks * 4 + hi;
                bf[ni] = *(const short8*)&Bs4[rb * 8 + (cb ^ (rb & 7))];
            }
#pragma unroll
            for (int mi = 0; mi < 2; mi++)
#pragma unroll
                for (int ni = 0; ni < CF; ni++)
                    acc[mi][ni] = __builtin_amdgcn_mfma_f32_16x16x32_bf16(af[mi], bf[ni], acc[mi][ni], 0, 0, 0);
        }
    }
    __syncthreads();

    // ---- epilogue: acc -> Es (=Bs region) bf16 [32][NB], R15 sw-XOR
    unsigned short* Es = BsMem;
#pragma unroll
    for (int mi = 0; mi < 2; mi++) {
        const int rowBase = mi * 16 + (hi << 2);
#pragma unroll
        for (int r = 0; r < 4; r++) {
            const int row = rowBase + r;
            const int sw  = ((row >> 2) & 3) << 4;
#pragma unroll
            for (int ni = 0; ni < CF; ni++) {
                const int c = wcb + ni * 16 + qm;
                Es[row * NB + (c ^ sw)] = f2b(acc[mi][ni][r]);
            }
        }
    }
    __syncthreads();

#define LOF(d) __uint_as_float((d) << 16)
#define HIF(d) __uint_as_float((d) & 0xffff0000u)
    if (DO == 128) {
        // T fp8: 32 rows x 8 chunks(16 dims) = 256 chunks, 1/thread (NT)
        unsigned char* T8o = (unsigned char*)Tout;
        {
            const int chunk = tid;
            const int row   = chunk >> 3;
            const int c0    = (chunk & 7) * 16;
            const int sw    = ((row >> 2) & 3) << 4;
            const int node  = m0 + row;
            if (node <= N_NODES) {
                ux4 v = (ux4)0u;
                if (node < N_NODES) {
                    const unsigned short* p = Es + row * 256 + (c0 ^ sw);
                    ux4 ha = *(const ux4*)p;
                    ux4 hb = *(const ux4*)(p + 8);
                    v.x = pack4_fp8(LOF(ha.x), HIF(ha.x), LOF(ha.y), HIF(ha.y));
                    v.y = pack4_fp8(LOF(ha.z), HIF(ha.z), LOF(ha.w), HIF(ha.w));
                    v.z = pack4_fp8(LOF(hb.x), HIF(hb.x), LOF(hb.y), HIF(hb.y));
                    v.w = pack4_fp8(LOF(hb.z), HIF(hb.z), LOF(hb.w), HIF(hb.w));
                }
                NTS(v, (ux4*)(T8o + (size_t)node * 128 + c0));
            }
        }
        // S bf16: cols 128..255 = 512 16B chunks, 2/thread (NT)
#pragma unroll
        for (int i = 0; i < 2; i++) {
            const int chunk = i * 256 + tid;
            const int row   = chunk >> 4;
            const int c0    = 128 + (chunk & 15) * 8;
            const int sw    = ((row >> 2) & 3) << 4;
            const int node  = m0 + row;
            if (node <= N_NODES) {
                ux4 v = (ux4)0u;
                if (node < N_NODES)
                    v = *(const ux4*)(Es + row * 256 + (c0 ^ sw));
                NTS(v, (ux4*)(Sout + (size_t)node * 128 + (c0 - 128)));
            }
        }
    } else {
        // DO=64: T fp8 cols 0..63 (threads 0..127) + S bf16 cols 64..127
        unsigned char* T8o = (unsigned char*)Tout;
        if (tid < 128) {
            const int row = tid >> 2;
            const int c0  = (tid & 3) * 16;
            const int sw  = ((row >> 2) & 3) << 4;
            const int node = m0 + row;
            if (node <= N_NODES) {
                ux4 v = (ux4)0u;
                if (node < N_NODES) {
                    const unsigned short* p = Es + row * 128 + (c0 ^ sw);
                    ux4 ha = *(const ux4*)p;
                    ux4 hb = *(const ux4*)(p + 8);
                    v.x = pack4_fp8(LOF(ha.x), HIF(ha.x), LOF(ha.y), HIF(ha.y));
                    v.y = pack4_fp8(LOF(ha.z), HIF(ha.z), LOF(ha.w), HIF(ha.w));
                    v.z = pack4_fp8(LOF(hb.x), HIF(hb.x), LOF(hb.y), HIF(hb.y));
                    v.w = pack4_fp8(LOF(hb.z), HIF(hb.z), LOF(hb.w), HIF(hb.w));
                }
                NTS(v, (ux4*)(T8o + (size_t)node * 64 + c0));
            }
        }
        {
            const int chunk = tid;               // 256 chunks
            const int row   = chunk >> 3;
            const int c0    = 64 + (chunk & 7) * 8;
            const int sw    = ((row >> 2) & 3) << 4;
            const int node  = m0 + row;
            if (node <= N_NODES) {
                ux4 v = (ux4)0u;
                if (node < N_NODES)
                    v = *(const ux4*)(Es + row * 128 + (c0 ^ sw));
                NTS(v, (ux4*)(Sout + (size_t)node * 64 + (c0 - 64)));
            }
        }
    }
#undef LOF
#undef HIF
}

// ---------------------------------------------------------------- final aggregate
// fp8 T3 row = 64B = 4 ux4. 16 lanes/node = 4 dim-quarters (bits 0,1)
// x 4 edge-groups (bits 2,3); merge shfl_xor(4,8); softmax shfl_xor(1,2).
// esrc uint16 (ux2 = 4 idx/load, NT); S loads NT; Fout stores NT.
__global__ __launch_bounds__(256) void agg_last_kernel(const unsigned char* __restrict__ T8,
                                                       const unsigned short* __restrict__ S,
                                                       const float* __restrict__ br,
                                                       const int* __restrict__ deg,
                                                       const unsigned short* __restrict__ esrc,
                                                       float* __restrict__ Fout) {
    const int lane16 = threadIdx.x & 15;
    const int dimq   = lane16 & 3;       // dims dimq*16..+15
    const int g      = lane16 >> 2;      // edge group 0..3
    const int n      = blockIdx.x * 16 + (threadIdx.x >> 4);

    int cnt = deg[n];
    if (cnt > ROW_CAP) cnt = ROW_CAP;
    const unsigned short* erow = esrc + (size_t)n * ROW_CAP;
    const ux4* T4 = (const ux4*)T8;      // fp8 row = 4 ux4

    v2f acc[8];
#pragma unroll
    for (int i = 0; i < 8; i++) acc[i] = (v2f)(0.0f);

    for (int o = g * 4; o < cnt; o += 16) {
        ux2 iv = NTL((const ux2*)(const void*)(erow + o));  // 4 idx
        unsigned j0 = iv.x & 0xffffu, j1 = iv.x >> 16;
        unsigned j2 = iv.y & 0xffffu, j3 = iv.y >> 16;
        j0 = (o + 0 < cnt) ? j0 : N_NODES;
        j1 = (o + 1 < cnt) ? j1 : N_NODES;
        j2 = (o + 2 < cnt) ? j2 : N_NODES;
        j3 = (o + 3 < cnt) ? j3 : N_NODES;
        ux4 q0 = T4[(size_t)j0 * 4 + dimq];
        ux4 q1 = T4[(size_t)j1 * 4 + dimq];
        ux4 q2 = T4[(size_t)j2 * 4 + dimq];
        ux4 q3 = T4[(size_t)j3 * 4 + dimq];
        addp16(acc, q0); addp16(acc, q1); addp16(acc, q2); addp16(acc, q3);
    }
    // merge the 4 edge groups (lane bits 2,3)
#pragma unroll
    for (int i = 0; i < 8; i++) {
        acc[i].x += __shfl_xor(acc[i].x, 4);
        acc[i].y += __shfl_xor(acc[i].y, 4);
        acc[i].x += __shfl_xor(acc[i].x, 8);
        acc[i].y += __shfl_xor(acc[i].y, 8);
    }

    // + S (bf16 exact, NT) + bias + relu: 16 dims per lane
    ux4 sv0 = NTL((const ux4*)S + (size_t)n * 8 + dimq * 2);
    ux4 sv1 = NTL((const ux4*)S + (size_t)n * 8 + dimq * 2 + 1);
    addp(acc, sv0); addp(acc + 4, sv1);

    const float4 b0 = ((const float4*)br)[dimq * 4];
    const float4 b1 = ((const float4*)br)[dimq * 4 + 1];
    const float4 b2 = ((const float4*)br)[dimq * 4 + 2];
    const float4 b3 = ((const float4*)br)[dimq * 4 + 3];

    float v[16];
    v[0]  = fmaxf(acc[0].x + b0.x, 0.f); v[1]  = fmaxf(acc[0].y + b0.y, 0.f);
    v[2]  = fmaxf(acc[1].x + b0.z, 0.f); v[3]  = fmaxf(acc[1].y + b0.w, 0.f);
    v[4]  = fmaxf(acc[2].x + b1.x, 0.f); v[5]  = fmaxf(acc[2].y + b1.y, 0.f);
    v[6]  = fmaxf(acc[3].x + b1.z, 0.f); v[7]  = fmaxf(acc[3].y + b1.w, 0.f);
    v[8]  = fmaxf(acc[4].x + b2.x, 0.f); v[9]  = fmaxf(acc[4].y + b2.y, 0.f);
    v[10] = fmaxf(acc[5].x + b2.z, 0.f); v[11] = fmaxf(acc[5].y + b2.w, 0.f);
    v[12] = fmaxf(acc[6].x + b3.x, 0.f); v[13] = fmaxf(acc[6].y + b3.y, 0.f);
    v[14] = fmaxf(acc[7].x + b3.z, 0.f); v[15] = fmaxf(acc[7].y + b3.w, 0.f);

    // log_softmax over 64 dims = 4 dimq lanes (lane bits 0,1)
    float m = v[0];
#pragma unroll
    for (int i = 1; i < 16; i++) m = fmaxf(m, v[i]);
    m = fmaxf(m, __shfl_xor(m, 1));
    m = fmaxf(m, __shfl_xor(m, 2));
    float es = 0.f;
#pragma unroll
    for (int i = 0; i < 16; i++) es += expf(v[i] - m);
    es += __shfl_xor(es, 1);
    es += __shfl_xor(es, 2);
    float lse = m + logf(es);

    if (g == 0) {
#pragma unroll
        for (int k = 0; k < 4; k++) {
            fx4 o = { v[k * 4 + 0] - lse, v[k * 4 + 1] - lse,
                      v[k * 4 + 2] - lse, v[k * 4 + 3] - lse };
            NTS(o, (fx4*)Fout + (size_t)n * 16 + dimq * 4 + k);
        }
    }
}

// ---------------------------------------------------------------- launch

extern "C" void kernel_launch(void* const* d_in, const int* in_sizes, int n_in,
                              void* d_out, int out_size, void* d_ws, size_t ws_size,
                              hipStream_t stream) {
    const float* x    = (const float*)d_in[0];
    const int*   eidx = (const int*)d_in[1];   // [2, E] int32
    const float* Wr0  = (const float*)d_in[2];
    const float* br0  = (const float*)d_in[3];
    const float* Ws0  = (const float*)d_in[4];
    const float* Wr1  = (const float*)d_in[5];
    const float* br1  = (const float*)d_in[6];
    const float* Ws1  = (const float*)d_in[7];
    const float* Wr2  = (const float*)d_in[8];
    const float* br2  = (const float*)d_in[9];
    const float* Ws2  = (const float*)d_in[10];
    float* out = (float*)d_out;

    const int* src = eidx;
    const int* dst = eidx + N_EDGES;

    auto align = [](size_t v) { return (v + 255) & ~(size_t)255; };
    char* w = (char*)d_ws;
    int* deg  = (int*)w;  w += align(sizeof(int) * DEG_CAP);
    unsigned short* esrc = (unsigned short*)w;
    w += align(sizeof(unsigned short) * (size_t)N_NODES * ROW_CAP);
    unsigned short* Wt0 = (unsigned short*)w;  w += align(2ull * 256 * 128);
    unsigned short* Wt1 = (unsigned short*)w;  w += align(2ull * 256 * 128);
    unsigned short* Wt2 = (unsigned short*)w;  w += align(2ull * 128 * 128);
    void* T_a = (void*)w;                      w += align(2ull * PAD_NODES * 64);  // fp8 128 / fp8 64
    void* T_b = (void*)w;                      w += align(2ull * PAD_NODES * 64);
    unsigned short* S_a = (unsigned short*)w;  w += align(2ull * PAD_NODES * 128);
    unsigned short* S_b = (unsigned short*)w;  w += align(2ull * PAD_NODES * 128);
    (void)ws_size; (void)n_in; (void)in_sizes; (void)out_size;

    // ---- deg zero (async memset) + fused prep/place
    (void)hipMemsetAsync(deg, 0, sizeof(int) * DEG_CAP, stream);
    prep_place_kernel<<<2820, 256, 0, stream>>>(
        src, dst, deg, esrc, Wr0, Ws0, Wr1, Ws1, Wr2, Ws2, Wt0, Wt1, Wt2);

    // ---- layer 1: mm only (fp32 x -> T_a fp8, S_a)
    mmf_kernel<128, false, true><<<PAD_NODES / 32, 256, 0, stream>>>(
        x, nullptr, nullptr, nullptr, nullptr, Wt0, T_a, S_a);

    // ---- layer 2: agg(L1) prologue + mm (T_a,S_a -> T_b fp8, S_b)
    mmf_kernel<128, true, false><<<PAD_NODES / 32, 256, 0, stream>>>(
        T_a, S_a, br0, deg, esrc, Wt1, T_b, S_b);

    // ---- layer 3: agg(L2) prologue + mm (T_b,S_b -> T_a fp8[64], S_a[64])
    mmf_kernel<64, true, false><<<PAD_NODES / 32, 256, 0, stream>>>(
        T_b, S_b, br1, deg, esrc, Wt2, T_a, S_a);

    // ---- final aggregate + log_softmax (fp8 T3, NT streams)
    agg_last_kernel<<<N_NODES / 16, 256, 0, stream>>>(
        (const unsigned char*)T_a, S_a, br2, deg, esrc, out);
}

// Round 15
// 185.804 us; speedup vs baseline: 1.0291x; 1.0291x over previous
//
#include <hip/hip_runtime.h>
#include <hip/hip_bf16.h>

// GraphConv x3 + ReLU + log_softmax on MI355X — bf16/MFMA pipeline.
// LEDGER (keep):
// R11/R16/R12: place fusion/spreading dead ends — place ~10us.
// R13/R14: quartered-T L2 pinning impossible; NT 2B SCALAR stores bad.
// R15 (WIN): swizzled-LDS transpose epilogue -> 16B coalesced stores.
// R17/R18/R22: gather currency = lines (1/edge floor reached) then
//      request count; fp8 T everywhere. R19: TLP beyond MSHR cap ~ 0.
// R20/R21 (WINs): agg fused as next mm's prologue; 32-row tiles (1.63
//      rounds); x fp32-direct; prep+place merged LDS-free.
// R23 (REGRESSION +7.5, mechanism found): NT on T/S stores evicts the
//      NEXT kernel's gather target from L2 (~1/8 hit rate lost). NT is
//      only safe on dead-after-use streams. Cache-locality book CLOSED:
//      >1/8 hit rate needs graph partitioning.
// R24: R22 structure + uint16 esrc + NT ONLY on x loads / Fout stores.
//      If ~183: structural floor reached -> ROOFLINE next.

#define N_NODES 40000
#define N_EDGES 640000
#define PAD_NODES 40064        // 1252 * 32
#define DEG_CAP   40960
#define ROW_CAP   64           // esrc slots per node

typedef float v4f __attribute__((ext_vector_type(4)));
typedef float v2f __attribute__((ext_vector_type(2)));
typedef short short8 __attribute__((ext_vector_type(8)));
typedef unsigned ux4 __attribute__((ext_vector_type(4)));
typedef unsigned ux2 __attribute__((ext_vector_type(2)));
typedef float fx4 __attribute__((ext_vector_type(4)));

#define NTL(p)    __builtin_nontemporal_load(p)
#define NTS(v, p) __builtin_nontemporal_store(v, p)

__device__ inline unsigned short f2b(float f) {  // RNE fp32->bf16
    unsigned u = __float_as_uint(f);
    return (unsigned short)((u + 0x7fffu + ((u >> 16) & 1u)) >> 16);
}

// bf16 -> fp8 e4m3 (OCP), RNE, FTZ below 2^-6, clamp 448 (fallback path).
__device__ inline unsigned b2f8(unsigned short us) {
    unsigned s  = ((unsigned)us >> 8) & 0x80u;
    unsigned mag = us & 0x7fffu;
    unsigned e8 = mag >> 7, m7 = mag & 0x7fu;
    unsigned out;
    if (e8 < 121u) out = 0u;
    else if (e8 > 135u) out = 0x7eu;
    else {
        unsigned e4 = e8 - 120u;
        unsigned r  = (m7 + 7u + ((m7 >> 4) & 1u)) >> 4;
        if (r == 8u) { r = 0u; e4++; }
        out = (e4 > 15u || (e4 == 15u && r > 6u)) ? 0x7eu : ((e4 << 3) | r);
    }
    return s | out;
}

__device__ inline unsigned pack4_fp8(float f0, float f1, float f2, float f3) {
#if __has_builtin(__builtin_amdgcn_cvt_pk_fp8_f32)
    int w = __builtin_amdgcn_cvt_pk_fp8_f32(f0, f1, 0, false);
    w = __builtin_amdgcn_cvt_pk_fp8_f32(f2, f3, w, true);
    return (unsigned)w;
#else
    return b2f8(f2b(f0)) | (b2f8(f2b(f1)) << 8) |
           (b2f8(f2b(f2)) << 16) | (b2f8(f2b(f3)) << 24);
#endif
}

#if __has_builtin(__builtin_amdgcn_cvt_f32_fp8)
#define F8TOF(w, sel) __builtin_amdgcn_cvt_f32_fp8((int)(w), (sel))
#else
__device__ inline float f8tof_(unsigned b) {
    unsigned e = (b >> 3) & 15u;
    unsigned bits = ((b & 0x80u) << 24) |
                    (e ? (((e + 120u) << 23) | ((b & 7u) << 20)) : 0u);
    return __uint_as_float(bits);
}
#define F8TOF(w, sel) f8tof_(((unsigned)(w) >> ((sel) * 8)) & 0xffu)
#endif

__device__ inline void addp(v2f* a, ux4 q) {         // 8 bf16
    v2f t0 = { __uint_as_float(q.x << 16), __uint_as_float(q.x & 0xffff0000u) };
    v2f t1 = { __uint_as_float(q.y << 16), __uint_as_float(q.y & 0xffff0000u) };
    v2f t2 = { __uint_as_float(q.z << 16), __uint_as_float(q.z & 0xffff0000u) };
    v2f t3 = { __uint_as_float(q.w << 16), __uint_as_float(q.w & 0xffff0000u) };
    a[0] += t0; a[1] += t1; a[2] += t2; a[3] += t3;
}
// 4 fp8 -> 2 v2f; packed-cvt path does 2 fp8 per instruction.
__device__ inline void addp8w(v2f* a, unsigned w) {
#if __has_builtin(__builtin_amdgcn_cvt_pk_f32_fp8)
    v2f lo = __builtin_amdgcn_cvt_pk_f32_fp8((int)w, false);
    v2f hi = __builtin_amdgcn_cvt_pk_f32_fp8((int)w, true);
    a[0] += lo; a[1] += hi;
#else
    v2f t0 = { F8TOF(w, 0), F8TOF(w, 1) };
    v2f t1 = { F8TOF(w, 2), F8TOF(w, 3) };
    a[0] += t0; a[1] += t1;
#endif
}
__device__ inline void addp16(v2f* a, ux4 q) {       // 16 fp8 -> a[0..7]
    addp8w(a + 0, q.x); addp8w(a + 2, q.y);
    addp8w(a + 4, q.z); addp8w(a + 6, q.w);
}

// ---------------------------------------------------------------- prep+place
// LDS-free fused kernel: blocks [0,2500) place edges (full occupancy);
// blocks [2500,2820) do W casts. deg zeroed by hipMemsetAsync.
// esrc uint16; src/dst loads NT (read once); scatter store cached.
__global__ __launch_bounds__(256) void prep_place_kernel(const int* __restrict__ src,
                                                         const int* __restrict__ dst,
                                                         int* __restrict__ deg,
                                                         unsigned short* __restrict__ esrc,
                                                         const float* __restrict__ Wr0, const float* __restrict__ Ws0,
                                                         const float* __restrict__ Wr1, const float* __restrict__ Ws1,
                                                         const float* __restrict__ Wr2, const float* __restrict__ Ws2,
                                                         unsigned short* __restrict__ Wt0,
                                                         unsigned short* __restrict__ Wt1,
                                                         unsigned short* __restrict__ Wt2) {
    const int bid = blockIdx.x;
    if (bid < 2500) {
        int e = bid * 256 + threadIdx.x;
        if (e < N_EDGES) {
            int d = NTL(dst + e);
            int s = NTL(src + e);
            int r = atomicAdd(&deg[d], 1);
            if (r < ROW_CAP) esrc[(size_t)d * ROW_CAP + r] = (unsigned short)s;
        }
    } else {
        int t = (bid - 2500) * 256 + threadIdx.x;   // 0..81919
        if (t < 32768) {
            int n = t >> 7, k = t & 127;
            const float* W = (n < 128) ? Wr0 : Ws0;
            Wt0[t] = f2b(W[k * 128 + (n & 127)]);
        } else if (t < 65536) {
            int u = t - 32768;
            int n = u >> 7, k = u & 127;
            const float* W = (n < 128) ? Wr1 : Ws1;
            Wt1[u] = f2b(W[k * 128 + (n & 127)]);
        } else if (t < 81920) {
            int u = t - 65536;
            int n = u >> 7, k = u & 127;
            const float* W = (n < 64) ? Wr2 : Ws2;
            Wt2[u] = f2b(W[k * 64 + (n & 63)]);
        }
    }
}

// ---------------------------------------------------------------- fused mm
// Block owns 32 rows x full NB=2*DO cols; grid 1252; LDS = As 8KB +
// Bs 32/16KB; (256,3) -> 1.63 rounds. AGG: 8 lanes/node x 16 dims,
// 1 ux4/edge/lane fp8 gather (line floor). F32: stage fp32 x (NT — dead
// after use). T/S stores CACHED (next kernel's gather/read target — R23
// lesson). node==N_NODES row forced zeros (dummy row for pad slots).
template <int DO, bool AGG, bool F32>
__global__ __launch_bounds__(256, 3) void mmf_kernel(const void* __restrict__ Ain,
                                                     const unsigned short* __restrict__ Sprev,
                                                     const float* __restrict__ brp,
                                                     const int* __restrict__ deg,
                                                     const unsigned short* __restrict__ esrc,
                                                     const unsigned short* __restrict__ Wt,
                                                     void* __restrict__ Tout,
                                                     unsigned short* __restrict__ Sout) {
    constexpr int NB  = 2 * DO;          // 256 or 128
    constexpr int NBW = NB / 4;          // cols per wave
    constexpr int CF  = NBW / 16;        // col frags per wave (4 or 2)

    __shared__ unsigned short AsMem[32 * 128];   // 8 KB
    __shared__ unsigned short BsMem[NB * 64];    // 32 KB (NB=256) / 16 KB
    ux4* As4 = (ux4*)AsMem;
    ux4* Bs4 = (ux4*)BsMem;

    const int tid  = threadIdx.x;
    const int m0   = blockIdx.x * 32;
    const int wave = tid >> 6;
    const int lane = tid & 63;
    const int qm   = lane & 15;
    const int hi   = lane >> 4;
    const int wcb  = wave * NBW;

    // ---- A: aggregate prologue / fp32 stage (gathers issued first)
    if (AGG) {
        const int noderow = tid >> 3;    // 0..31
        const int lane8   = tid & 7;     // dims lane8*16..+15
        const int n       = m0 + noderow;
        if (n < N_NODES) {
            int cnt = deg[n];
            if (cnt > ROW_CAP) cnt = ROW_CAP;
            const unsigned short* erow = esrc + (size_t)n * ROW_CAP;
            const ux4* T8 = (const ux4*)Ain;  // fp8 row = 8 ux4
            v2f acc[8];
#pragma unroll
            for (int i = 0; i < 8; i++) acc[i] = (v2f)(0.0f);
            for (int o = 0; o < cnt; o += 8) {
                ux4 iv = *(const ux4*)(const void*)(erow + o);  // 8 idx
                unsigned j0 = iv.x & 0xffffu, j1 = iv.x >> 16;
                unsigned j2 = iv.y & 0xffffu, j3 = iv.y >> 16;
                unsigned j4 = iv.z & 0xffffu, j5 = iv.z >> 16;
                unsigned j6 = iv.w & 0xffffu, j7 = iv.w >> 16;
                j0 = (o + 0 < cnt) ? j0 : N_NODES;
                j1 = (o + 1 < cnt) ? j1 : N_NODES;
                j2 = (o + 2 < cnt) ? j2 : N_NODES;
                j3 = (o + 3 < cnt) ? j3 : N_NODES;
                j4 = (o + 4 < cnt) ? j4 : N_NODES;
                j5 = (o + 5 < cnt) ? j5 : N_NODES;
                j6 = (o + 6 < cnt) ? j6 : N_NODES;
                j7 = (o + 7 < cnt) ? j7 : N_NODES;
                ux4 q0 = T8[(size_t)j0 * 8 + lane8];
                ux4 q1 = T8[(size_t)j1 * 8 + lane8];
                ux4 q2 = T8[(size_t)j2 * 8 + lane8];
                ux4 q3 = T8[(size_t)j3 * 8 + lane8];
                ux4 q4 = T8[(size_t)j4 * 8 + lane8];
                ux4 q5 = T8[(size_t)j5 * 8 + lane8];
                ux4 q6 = T8[(size_t)j6 * 8 + lane8];
                ux4 q7 = T8[(size_t)j7 * 8 + lane8];
                addp16(acc, q0); addp16(acc, q1); addp16(acc, q2); addp16(acc, q3);
                addp16(acc, q4); addp16(acc, q5); addp16(acc, q6); addp16(acc, q7);
            }
            // + S (bf16 exact) + bias, relu, pack 16 dims -> 2 ux4
            ux4 sv0 = *((const ux4*)Sprev + (size_t)n * 16 + lane8 * 2);
            ux4 sv1 = *((const ux4*)Sprev + (size_t)n * 16 + lane8 * 2 + 1);
            addp(acc, sv0); addp(acc + 4, sv1);
            float vv[16];
#pragma unroll
            for (int j = 0; j < 16; j++) {
                float bj = brp[lane8 * 16 + j];
                vv[j] = fmaxf(((j & 1) ? acc[j >> 1].y : acc[j >> 1].x) + bj, 0.f);
            }
#pragma unroll
            for (int h = 0; h < 2; h++) {
                ux4 o;
                o.x = (unsigned)f2b(vv[h * 8 + 0]) | ((unsigned)f2b(vv[h * 8 + 1]) << 16);
                o.y = (unsigned)f2b(vv[h * 8 + 2]) | ((unsigned)f2b(vv[h * 8 + 3]) << 16);
                o.z = (unsigned)f2b(vv[h * 8 + 4]) | ((unsigned)f2b(vv[h * 8 + 5]) << 16);
                o.w = (unsigned)f2b(vv[h * 8 + 6]) | ((unsigned)f2b(vv[h * 8 + 7]) << 16);
                As4[noderow * 16 + ((lane8 * 2 + h) ^ (noderow & 7))] = o;
            }
        } else {
            ux4 z = (ux4)0u;
#pragma unroll
            for (int h = 0; h < 2; h++)
                As4[noderow * 16 + ((lane8 * 2 + h) ^ (noderow & 7))] = z;
        }
    } else if (F32) {
        const fx4* Xg = (const fx4*)Ain;             // row pitch 32 fx4
#pragma unroll
        for (int i = 0; i < 2; i++) {
            int idx = i * 256 + tid;                 // ux4 slot 0..511
            int row = idx >> 4, c = idx & 15;        // c = 8-dim chunk
            int gr = m0 + row;
            if (gr > N_NODES - 1) gr = N_NODES - 1;  // pad clamp
            fx4 a = NTL(Xg + (size_t)gr * 32 + c * 2);      // x dead after use
            fx4 b = NTL(Xg + (size_t)gr * 32 + c * 2 + 1);
            ux4 o;
            o.x = (unsigned)f2b(a.x) | ((unsigned)f2b(a.y) << 16);
            o.y = (unsigned)f2b(a.z) | ((unsigned)f2b(a.w) << 16);
            o.z = (unsigned)f2b(b.x) | ((unsigned)f2b(b.y) << 16);
            o.w = (unsigned)f2b(b.z) | ((unsigned)f2b(b.w) << 16);
            As4[row * 16 + (c ^ (row & 7))] = o;
        }
    } else {
        const unsigned short* Ab = (const unsigned short*)Ain;
#pragma unroll
        for (int i = 0; i < 2; i++) {
            int idx = i * 256 + tid;
            int row = idx >> 4, c = idx & 15;
            int gr = m0 + row;
            if (gr > N_NODES - 1) gr = N_NODES - 1;
            As4[row * 16 + (c ^ (row & 7))] =
                *(const ux4*)(const void*)(Ab + (size_t)gr * 128 + c * 8);
        }
    }

    // ---- stage B half 0 (cached — reused by all blocks)
#pragma unroll
    for (int i = 0; i < NB * 8 / 256; i++) {
        int idx = i * 256 + tid;
        int row = idx >> 3, c8 = idx & 7;
        Bs4[row * 8 + (c8 ^ (row & 7))] =
            *(const ux4*)(Wt + (size_t)row * 128 + c8 * 8);
    }
    __syncthreads();

    // ---- MFMA: K=128 in 2 halves; Bs restaged between halves
    v4f acc[2][CF];
#pragma unroll
    for (int i = 0; i < 2; i++)
#pragma unroll
        for (int j = 0; j < CF; j++) acc[i][j] = (v4f)(0.0f);

#pragma unroll
    for (int half = 0; half < 2; half++) {
        if (half == 1) {
            __syncthreads();
#pragma unroll
            for (int i = 0; i < NB * 8 / 256; i++) {
                int idx = i * 256 + tid;
                int row = idx >> 3, c8 = idx & 7;
                Bs4[row * 8 + (c8 ^ (row & 7))] =
                    *(const ux4*)(Wt + (size_t)row * 128 + 64 + c8 * 8);
            }
            __syncthreads();
        }
#pragma unroll
        for (int ks = 0; ks < 2; ks++) {
            short8 af[2], bf[CF];
#pragma unroll
            for (int mi = 0; mi < 2; mi++) {
                const int r  = mi * 16 + qm;
                const int ca = half * 8 + ks * 4 + hi;
                af[mi] = *(const short8*)&As4[r * 16 + (ca ^ (r & 7))];
            }
#pragma unroll
            for (int ni = 0; ni < CF; ni++) {
                const int rb = wcb + ni * 16 + qm;
                const int cb = ks * 4 + hi;
                bf[ni] = *(const short8*)&Bs4[rb * 8 + (cb ^ (rb & 7))];
            }
#pragma unroll
            for (int mi = 0; mi < 2; mi++)
#pragma unroll
                for (int ni = 0; ni < CF; ni++)
                    acc[mi][ni] = __builtin_amdgcn_mfma_f32_16x16x32_bf16(af[mi], bf[ni], acc[mi][ni], 0, 0, 0);
        }
    }
    __syncthreads();

    // ---- epilogue: acc -> Es (=Bs region) bf16 [32][NB], R15 sw-XOR
    unsigned short* Es = BsMem;
#pragma unroll
    for (int mi = 0; mi < 2; mi++) {
        const int rowBase = mi * 16 + (hi << 2);
#pragma unroll
        for (int r = 0; r < 4; r++) {
            const int row = rowBase + r;
            const int sw  = ((row >> 2) & 3) << 4;
#pragma unroll
            for (int ni = 0; ni < CF; ni++) {
                const int c = wcb + ni * 16 + qm;
                Es[row * NB + (c ^ sw)] = f2b(acc[mi][ni][r]);
            }
        }
    }
    __syncthreads();

#define LOF(d) __uint_as_float((d) << 16)
#define HIF(d) __uint_as_float((d) & 0xffff0000u)
    if (DO == 128) {
        // T fp8: 32 rows x 8 chunks(16 dims) = 256 chunks, 1/thread (cached)
        unsigned char* T8o = (unsigned char*)Tout;
        {
            const int chunk = tid;
            const int row   = chunk >> 3;
            const int c0    = (chunk & 7) * 16;
            const int sw    = ((row >> 2) & 3) << 4;
            const int node  = m0 + row;
            if (node <= N_NODES) {
                ux4 v = (ux4)0u;
                if (node < N_NODES) {
                    const unsigned short* p = Es + row * 256 + (c0 ^ sw);
                    ux4 ha = *(const ux4*)p;
                    ux4 hb = *(const ux4*)(p + 8);
                    v.x = pack4_fp8(LOF(ha.x), HIF(ha.x), LOF(ha.y), HIF(ha.y));
                    v.y = pack4_fp8(LOF(ha.z), HIF(ha.z), LOF(ha.w), HIF(ha.w));
                    v.z = pack4_fp8(LOF(hb.x), HIF(hb.x), LOF(hb.y), HIF(hb.y));
                    v.w = pack4_fp8(LOF(hb.z), HIF(hb.z), LOF(hb.w), HIF(hb.w));
                }
                *(ux4*)(T8o + (size_t)node * 128 + c0) = v;
            }
        }
        // S bf16: cols 128..255 = 512 16B chunks, 2/thread (cached)
#pragma unroll
        for (int i = 0; i < 2; i++) {
            const int chunk = i * 256 + tid;
            const int row   = chunk >> 4;
            const int c0    = 128 + (chunk & 15) * 8;
            const int sw    = ((row >> 2) & 3) << 4;
            const int node  = m0 + row;
            if (node <= N_NODES) {
                ux4 v = (ux4)0u;
                if (node < N_NODES)
                    v = *(const ux4*)(Es + row * 256 + (c0 ^ sw));
                *(ux4*)(Sout + (size_t)node * 128 + (c0 - 128)) = v;
            }
        }
    } else {
        // DO=64: T fp8 cols 0..63 (threads 0..127) + S bf16 cols 64..127
        unsigned char* T8o = (unsigned char*)Tout;
        if (tid < 128) {
            const int row = tid >> 2;
            const int c0  = (tid & 3) * 16;
            const int sw  = ((row >> 2) & 3) << 4;
            const int node = m0 + row;
            if (node <= N_NODES) {
                ux4 v = (ux4)0u;
                if (node < N_NODES) {
                    const unsigned short* p = Es + row * 128 + (c0 ^ sw);
                    ux4 ha = *(const ux4*)p;
                    ux4 hb = *(const ux4*)(p + 8);
                    v.x = pack4_fp8(LOF(ha.x), HIF(ha.x), LOF(ha.y), HIF(ha.y));
                    v.y = pack4_fp8(LOF(ha.z), HIF(ha.z), LOF(ha.w), HIF(ha.w));
                    v.z = pack4_fp8(LOF(hb.x), HIF(hb.x), LOF(hb.y), HIF(hb.y));
                    v.w = pack4_fp8(LOF(hb.z), HIF(hb.z), LOF(hb.w), HIF(hb.w));
                }
                *(ux4*)(T8o + (size_t)node * 64 + c0) = v;
            }
        }
        {
            const int chunk = tid;               // 256 chunks
            const int row   = chunk >> 3;
            const int c0    = 64 + (chunk & 7) * 8;
            const int sw    = ((row >> 2) & 3) << 4;
            const int node  = m0 + row;
            if (node <= N_NODES) {
                ux4 v = (ux4)0u;
                if (node < N_NODES)
                    v = *(const ux4*)(Es + row * 128 + (c0 ^ sw));
                *(ux4*)(Sout + (size_t)node * 64 + (c0 - 64)) = v;
            }
        }
    }
#undef LOF
#undef HIF
}

// ---------------------------------------------------------------- final aggregate
// fp8 T3 row = 64B = 4 ux4. 16 lanes/node = 4 dim-quarters (bits 0,1)
// x 4 edge-groups (bits 2,3); merge shfl_xor(4,8); softmax shfl_xor(1,2).
// esrc uint16 (ux2 = 4 idx/load, cached); Fout stores NT (dead after use).
__global__ __launch_bounds__(256) void agg_last_kernel(const unsigned char* __restrict__ T8,
                                                       const unsigned short* __restrict__ S,
                                                       const float* __restrict__ br,
                                                       const int* __restrict__ deg,
                                                       const unsigned short* __restrict__ esrc,
                                                       float* __restrict__ Fout) {
    const int lane16 = threadIdx.x & 15;
    const int dimq   = lane16 & 3;       // dims dimq*16..+15
    const int g      = lane16 >> 2;      // edge group 0..3
    const int n      = blockIdx.x * 16 + (threadIdx.x >> 4);

    int cnt = deg[n];
    if (cnt > ROW_CAP) cnt = ROW_CAP;
    const unsigned short* erow = esrc + (size_t)n * ROW_CAP;
    const ux4* T4 = (const ux4*)T8;      // fp8 row = 4 ux4

    v2f acc[8];
#pragma unroll
    for (int i = 0; i < 8; i++) acc[i] = (v2f)(0.0f);

    for (int o = g * 4; o < cnt; o += 16) {
        ux2 iv = *(const ux2*)(const void*)(erow + o);  // 4 idx
        unsigned j0 = iv.x & 0xffffu, j1 = iv.x >> 16;
        unsigned j2 = iv.y & 0xffffu, j3 = iv.y >> 16;
        j0 = (o + 0 < cnt) ? j0 : N_NODES;
        j1 = (o + 1 < cnt) ? j1 : N_NODES;
        j2 = (o + 2 < cnt) ? j2 : N_NODES;
        j3 = (o + 3 < cnt) ? j3 : N_NODES;
        ux4 q0 = T4[(size_t)j0 * 4 + dimq];
        ux4 q1 = T4[(size_t)j1 * 4 + dimq];
        ux4 q2 = T4[(size_t)j2 * 4 + dimq];
        ux4 q3 = T4[(size_t)j3 * 4 + dimq];
        addp16(acc, q0); addp16(acc, q1); addp16(acc, q2); addp16(acc, q3);
    }
    // merge the 4 edge groups (lane bits 2,3)
#pragma unroll
    for (int i = 0; i < 8; i++) {
        acc[i].x += __shfl_xor(acc[i].x, 4);
        acc[i].y += __shfl_xor(acc[i].y, 4);
        acc[i].x += __shfl_xor(acc[i].x, 8);
        acc[i].y += __shfl_xor(acc[i].y, 8);
    }

    // + S (bf16 exact) + bias + relu: 16 dims per lane
    ux4 sv0 = *((const ux4*)S + (size_t)n * 8 + dimq * 2);
    ux4 sv1 = *((const ux4*)S + (size_t)n * 8 + dimq * 2 + 1);
    addp(acc, sv0); addp(acc + 4, sv1);

    const float4 b0 = ((const float4*)br)[dimq * 4];
    const float4 b1 = ((const float4*)br)[dimq * 4 + 1];
    const float4 b2 = ((const float4*)br)[dimq * 4 + 2];
    const float4 b3 = ((const float4*)br)[dimq * 4 + 3];

    float v[16];
    v[0]  = fmaxf(acc[0].x + b0.x, 0.f); v[1]  = fmaxf(acc[0].y + b0.y, 0.f);
    v[2]  = fmaxf(acc[1].x + b0.z, 0.f); v[3]  = fmaxf(acc[1].y + b0.w, 0.f);
    v[4]  = fmaxf(acc[2].x + b1.x, 0.f); v[5]  = fmaxf(acc[2].y + b1.y, 0.f);
    v[6]  = fmaxf(acc[3].x + b1.z, 0.f); v[7]  = fmaxf(acc[3].y + b1.w, 0.f);
    v[8]  = fmaxf(acc[4].x + b2.x, 0.f); v[9]  = fmaxf(acc[4].y + b2.y, 0.f);
    v[10] = fmaxf(acc[5].x + b2.z, 0.f); v[11] = fmaxf(acc[5].y + b2.w, 0.f);
    v[12] = fmaxf(acc[6].x + b3.x, 0.f); v[13] = fmaxf(acc[6].y + b3.y, 0.f);
    v[14] = fmaxf(acc[7].x + b3.z, 0.f); v[15] = fmaxf(acc[7].y + b3.w, 0.f);

    // log_softmax over 64 dims = 4 dimq lanes (lane bits 0,1)
    float m = v[0];
#pragma unroll
    for (int i = 1; i < 16; i++) m = fmaxf(m, v[i]);
    m = fmaxf(m, __shfl_xor(m, 1));
    m = fmaxf(m, __shfl_xor(m, 2));
    float es = 0.f;
#pragma unroll
    for (int i = 0; i < 16; i++) es += expf(v[i] - m);
    es += __shfl_xor(es, 1);
    es += __shfl_xor(es, 2);
    float lse = m + logf(es);

    if (g == 0) {
#pragma unroll
        for (int k = 0; k < 4; k++) {
            fx4 o = { v[k * 4 + 0] - lse, v[k * 4 + 1] - lse,
                      v[k * 4 + 2] - lse, v[k * 4 + 3] - lse };
            NTS(o, (fx4*)Fout + (size_t)n * 16 + dimq * 4 + k);
        }
    }
}

// ---------------------------------------------------------------- launch

extern "C" void kernel_launch(void* const* d_in, const int* in_sizes, int n_in,
                              void* d_out, int out_size, void* d_ws, size_t ws_size,
                              hipStream_t stream) {
    const float* x    = (const float*)d_in[0];
    const int*   eidx = (const int*)d_in[1];   // [2, E] int32
    const float* Wr0  = (const float*)d_in[2];
    const float* br0  = (const float*)d_in[3];
    const float* Ws0  = (const float*)d_in[4];
    const float* Wr1  = (const float*)d_in[5];
    const float* br1  = (const float*)d_in[6];
    const float* Ws1  = (const float*)d_in[7];
    const float* Wr2  = (const float*)d_in[8];
    const float* br2  = (const float*)d_in[9];
    const float* Ws2  = (const float*)d_in[10];
    float* out = (float*)d_out;

    const int* src = eidx;
    const int* dst = eidx + N_EDGES;

    auto align = [](size_t v) { return (v + 255) & ~(size_t)255; };
    char* w = (char*)d_ws;
    int* deg  = (int*)w;  w += align(sizeof(int) * DEG_CAP);
    unsigned short* esrc = (unsigned short*)w;
    w += align(sizeof(unsigned short) * (size_t)N_NODES * ROW_CAP);
    unsigned short* Wt0 = (unsigned short*)w;  w += align(2ull * 256 * 128);
    unsigned short* Wt1 = (unsigned short*)w;  w += align(2ull * 256 * 128);
    unsigned short* Wt2 = (unsigned short*)w;  w += align(2ull * 128 * 128);
    void* T_a = (void*)w;                      w += align(2ull * PAD_NODES * 64);  // fp8 128 / fp8 64
    void* T_b = (void*)w;                      w += align(2ull * PAD_NODES * 64);
    unsigned short* S_a = (unsigned short*)w;  w += align(2ull * PAD_NODES * 128);
    unsigned short* S_b = (unsigned short*)w;  w += align(2ull * PAD_NODES * 128);
    (void)ws_size; (void)n_in; (void)in_sizes; (void)out_size;

    // ---- deg zero (async memset) + fused prep/place
    (void)hipMemsetAsync(deg, 0, sizeof(int) * DEG_CAP, stream);
    prep_place_kernel<<<2820, 256, 0, stream>>>(
        src, dst, deg, esrc, Wr0, Ws0, Wr1, Ws1, Wr2, Ws2, Wt0, Wt1, Wt2);

    // ---- layer 1: mm only (fp32 x -> T_a fp8, S_a)
    mmf_kernel<128, false, true><<<PAD_NODES / 32, 256, 0, stream>>>(
        x, nullptr, nullptr, nullptr, nullptr, Wt0, T_a, S_a);

    // ---- layer 2: agg(L1) prologue + mm (T_a,S_a -> T_b fp8, S_b)
    mmf_kernel<128, true, false><<<PAD_NODES / 32, 256, 0, stream>>>(
        T_a, S_a, br0, deg, esrc, Wt1, T_b, S_b);

    // ---- layer 3: agg(L2) prologue + mm (T_b,S_b -> T_a fp8[64], S_a[64])
    mmf_kernel<64, true, false><<<PAD_NODES / 32, 256, 0, stream>>>(
        T_b, S_b, br1, deg, esrc, Wt2, T_a, S_a);

    // ---- final aggregate + log_softmax (fp8 T3)
    agg_last_kernel<<<N_NODES / 16, 256, 0, stream>>>(
        (const unsigned char*)T_a, S_a, br2, deg, esrc, out);
}